// Round 3
// baseline (454.383 us; speedup 1.0000x reference)
//
#include <hip/hip_runtime.h>
#include <stdint.h>

// Problem constants
#define B 2048
#define S 201
#define HALF 100                 // S/2
#define D 128
#define BS (B * S)               // 411648
#define OFF_POS (BS * D)         // 52690944  : pos_enc starts here (floats)
#define OFF_VT  (2 * OFF_POS)    // 105381888 : visited_time (floats)
#define OFF_T2  (OFF_VT + BS)    // 105793536 : top2 (floats, 2 per bs)
#define F4B (S * (D / 4))        // 6432      : float4 elements per batch in [B,S,D]
#define TPB 256
#define NBLK (B / 2)             // 1024 blocks, 2 batches each -> ONE generation/CU

typedef float vf4 __attribute__((ext_vector_type(4)));
typedef float vf2 __attribute__((ext_vector_type(2)));

// Serial stack-sim chase for one batch: fills vis[] (visit times), t2[] (top2
// packed head|second<<8). nx/pv = doubly-linked list over open pickups;
// m0/m1 = membership bitmask. Logic identical to the verified round-1 kernel.
__device__ __forceinline__ void chase(const uint8_t* __restrict__ sl,
                                      uint8_t* __restrict__ vis,
                                      uint16_t* __restrict__ t2,
                                      uint8_t* __restrict__ nx,
                                      uint8_t* __restrict__ pv) {
    int pre = 0;
    int head = 0, second = 1;  // head==0 -> second==1; 1 open -> second==0
    unsigned long long m0 = 0, m1 = 0;  // in-list bitmask, pickups 1..100
    for (int i = 0; i < S; ++i) {
        int cur = sl[pre];
        vis[cur] = (uint8_t)(i + 1);
        if (cur != 0) {
            if (cur <= HALF) {
                // push: new element is the new maximum (time i+1)
                nx[cur]  = (uint8_t)head;
                pv[head] = (uint8_t)cur;   // pv[0] harmless
                second = head;
                head   = cur;
                if (cur < 64) m0 |= 1ull << cur; else m1 |= 1ull << (cur - 64);
            } else {
                int q = cur - HALF;        // 1..100
                bool in = (q < 64) ? ((m0 >> q) & 1ull) : ((m1 >> (q - 64)) & 1ull);
                if (in) {
                    if (q < 64) m0 &= ~(1ull << q); else m1 &= ~(1ull << (q - 64));
                    if (q == head) {
                        head = second;
                        second = (head == 0) ? 1 : (int)nx[head];
                    } else if (q == second) {
                        int n2 = nx[q];
                        nx[head] = (uint8_t)n2;
                        pv[n2]   = (uint8_t)head;
                        second = n2;
                    } else {
                        int p = pv[q], n2 = nx[q];
                        nx[p]  = (uint8_t)n2;
                        pv[n2] = (uint8_t)p;
                    }
                }
            }
        }
        t2[cur] = (uint16_t)(head | (second << 8));
        pre = cur;
    }
}

// ROUND 2 CHANGE: software-pipeline TWO batches per block (1024 blocks = exactly
// one resident generation at 4 blocks/CU). P1: two chases run in PARALLEL on
// lane 0 of waves 0 and 1 while threads 128-255 stream xemb for both batches
// (~34us of BW share hides the ~15us chase). P2: all 256 threads stream both
// pos_enc tiles + dumps. Removes the 2x chase-gated dead window of round 1.
__global__ __launch_bounds__(TPB, 4) void fused(const float* __restrict__ x,
                                                const int* __restrict__ sol,
                                                const float* __restrict__ W,
                                                const float* __restrict__ pattern,
                                                float* __restrict__ out) {
    __shared__ uint8_t  s_sol[2][S];
    __shared__ uint8_t  s_vis[2][S];
    __shared__ uint16_t s_t2 [2][S];
    __shared__ uint8_t  s_nx [2][HALF + 1];
    __shared__ uint8_t  s_pv [2][HALF + 1];

    const int tid = threadIdx.x;
    const int b0  = blockIdx.x;
    const int b1  = blockIdx.x + NBLK;

    // stage both sol rows (coalesced) + zero vis/t2
    for (int j = tid; j < S; j += TPB) {
        s_sol[0][j] = (uint8_t)sol[b0 * S + j];
        s_sol[1][j] = (uint8_t)sol[b1 * S + j];
        s_vis[0][j] = 0;  s_vis[1][j] = 0;
        s_t2 [0][j] = 0;  s_t2 [1][j] = 0;
    }
    __syncthreads();

    if (tid < 128) {
        // waves 0,1: lane 0 of each runs one chase (divergence-free serial chain)
        if ((tid & 63) == 0) {
            const int w = tid >> 6;  // 0 or 1
            chase(s_sol[w], s_vis[w], s_t2[w], s_nx[w], s_pv[w]);
        }
    } else {
        // threads 128-255: x_embedding for BOTH batches (vt-independent)
        const int t  = tid - 128;        // 0..127, stride multiple of 32
        const int d4 = t & 31;
        const float4* W4 = (const float4*)W;
        float4 w0 = W4[d4 * 2];          // {W[4d4][0],W[4d4][1],W[4d4+1][0],W[4d4+1][1]}
        float4 w1 = W4[d4 * 2 + 1];
        #pragma unroll
        for (int h = 0; h < 2; ++h) {
            const int b = h ? b1 : b0;
            const float2* x2 = (const float2*)x + b * S;   // L1-hot
            vf4* o4 = (vf4*)out + b * F4B;
            for (int idx4 = t; idx4 < F4B; idx4 += 128) {
                float2 xv = x2[idx4 >> 5];
                vf4 o;
                o.x = xv.x * w0.x + xv.y * w0.y;
                o.y = xv.x * w0.z + xv.y * w0.w;
                o.z = xv.x * w1.x + xv.y * w1.y;
                o.w = xv.x * w1.z + xv.y * w1.w;
                o4[idx4] = o;
            }
        }
    }
    __syncthreads();

    // P2: pos_enc for both batches (pattern 103 KB, L2-resident) + dumps
    const vf4* p4 = (const vf4*)pattern;
    #pragma unroll
    for (int h = 0; h < 2; ++h) {
        const int b = h ? b1 : b0;
        vf4* o4 = (vf4*)(out + OFF_POS) + b * F4B;
        for (int idx4 = tid; idx4 < F4B; idx4 += TPB) {
            int vt  = s_vis[h][idx4 >> 5];         // 1..201 (broadcast read)
            int row = (vt >= S) ? (vt - S) : vt;   // vt % S
            o4[idx4] = p4[row * 32 + (idx4 & 31)];
        }
        for (int j = tid; j < S; j += TPB) {
            out[OFF_VT + b * S + j] = (float)s_vis[h][j];
            int tt = s_t2[h][j];
            vf2 f2 = { (float)(tt & 255), (float)(tt >> 8) };
            ((vf2*)(out + OFF_T2))[b * S + j] = f2;
        }
    }
}

extern "C" void kernel_launch(void* const* d_in, const int* in_sizes, int n_in,
                              void* d_out, int out_size, void* d_ws, size_t ws_size,
                              hipStream_t stream) {
    const float* x       = (const float*)d_in[0];   // [2048,201,2] f32
    const int*   sol     = (const int*)d_in[1];     // [2048,201] int
    const float* W       = (const float*)d_in[2];   // [128,2] f32
    const float* pattern = (const float*)d_in[3];   // [201,128] f32
    float* out = (float*)d_out;

    hipLaunchKernelGGL(fused, dim3(NBLK), dim3(TPB), 0, stream, x, sol, W, pattern, out);
}

// Round 4
// 439.293 us; speedup vs baseline: 1.0344x; 1.0344x over previous
//
#include <hip/hip_runtime.h>
#include <stdint.h>

// Problem constants
#define B 2048
#define S 201
#define HALF 100                 // S/2
#define D 128
#define BS (B * S)               // 411648
#define OFF_POS (BS * D)         // 52690944  : pos_enc starts here (floats)
#define OFF_VT  (2 * OFF_POS)    // 105381888 : visited_time (floats)
#define OFF_T2  (OFF_VT + BS)    // 105793536 : top2 (floats, 2 per bs)
#define F4B (S * (D / 4))        // 6432      : float4 elements per batch in [B,S,D]
#define TPB 256

typedef float vf4 __attribute__((ext_vector_type(4)));
typedef float vf2 __attribute__((ext_vector_type(2)));

// ROUND 4: remove the stack simulation from the serial chain.
// Insight: reference's `stacks` is an array keyed by pickup q, and
// top2-at-step-i == arg-top2 of {0.0@idx0} U {vis[q] if open(q,t) else -0.01}
// with t = i+1 and open(q,t) = vis[q] <= t && !(vis[q] < vis[q+100] <= t).
// t2[c] is recorded at t = vis[c]. So after the bare pointer chase fills vis[],
// every node's top2 is independently computable by any thread (~1-2 us for all
// 201 nodes, wave-uniform broadcast LDS reads). Serial chain shrinks from
// ~40-50 us (branchy, 2-3 dependent LDS reads/iter) to ~11 us (1 ds_read_u8),
// now fully hidden under the xemb stream. LDS drops to 402 B ->
// __launch_bounds__(256,8): 8 blocks/CU, all 2048 blocks in ONE generation.
__global__ __launch_bounds__(TPB, 8) void fused(const float* __restrict__ x,
                                                const int* __restrict__ sol,
                                                const float* __restrict__ W,
                                                const float* __restrict__ pattern,
                                                float* __restrict__ out) {
    __shared__ uint8_t s_sol[S];
    __shared__ uint8_t s_vis[S];

    const int tid = threadIdx.x;
    const int b   = blockIdx.x;

    if (tid < 64) {
        // wave 0: stage sol (coalesced), then lane 0 runs the bare chase.
        for (int j = tid; j < S; j += 64)
            s_sol[j] = (uint8_t)sol[b * S + j];
        // wave-0 DS writes complete before lane 0's reads (same-wave, in-order DS)
        asm volatile("s_waitcnt lgkmcnt(0)" ::: "memory");
        if (tid == 0) {
            int pre = 0;
            #pragma unroll 1
            for (int i = 0; i < S; ++i) {
                int cur = s_sol[pre];          // the ONLY serial dependence
                s_vis[cur] = (uint8_t)(i + 1); // every node visited exactly once
                pre = cur;
            }
        }
    } else {
        // waves 1-3 (192 threads): x_embedding stream, vt-independent
        const int t  = tid - 64;          // 0..191, stride multiple of 32
        const int d4 = t & 31;
        const float4* W4 = (const float4*)W;
        float4 w0 = W4[d4 * 2];           // {W[4d4][0],W[4d4][1],W[4d4+1][0],W[4d4+1][1]}
        float4 w1 = W4[d4 * 2 + 1];
        const float2* x2 = (const float2*)x + b * S;
        vf4* o4 = (vf4*)out + b * F4B;
        for (int idx4 = t; idx4 < F4B; idx4 += 192) {
            float2 xv = x2[idx4 >> 5];
            vf4 o;
            o.x = xv.x * w0.x + xv.y * w0.y;
            o.y = xv.x * w0.z + xv.y * w0.w;
            o.z = xv.x * w1.x + xv.y * w1.y;
            o.w = xv.x * w1.z + xv.y * w1.w;
            o4[idx4] = o;
        }
    }
    __syncthreads();

    // P2a: per-node top2 (parallel, replaces serial stack sim) + vt dump.
    // All s_vis reads in the q-loop are wave-uniform -> broadcast, conflict-free.
    for (int c = tid; c < S; c += TPB) {
        int t = s_vis[c];                  // t = vis[c] in 1..201
        int best = 0, bi = 0, sec = -1, si = 1;  // {0.0@0} seed; -1 ~ -0.01
        #pragma unroll 4
        for (int q = 1; q <= HALF; ++q) {
            int vp = s_vis[q];
            int vd = s_vis[q + HALF];
            bool open = (vp <= t) && !((vp < vd) && (vd <= t));
            int v = open ? vp : -1;
            if (v > best) { sec = best; si = bi; best = v; bi = q; }
            else if (v > sec) { sec = v; si = q; }
        }
        out[OFF_VT + b * S + c] = (float)t;
        vf2 f2 = { (float)bi, (float)si };
        ((vf2*)(out + OFF_T2))[b * S + c] = f2;
    }

    // P2b: pos_enc stream (pattern 103 KB, L2-resident)
    {
        const vf4* p4 = (const vf4*)pattern;
        vf4* o4 = (vf4*)(out + OFF_POS) + b * F4B;
        for (int idx4 = tid; idx4 < F4B; idx4 += TPB) {
            int vt  = s_vis[idx4 >> 5];            // 1..201 (broadcast read)
            int row = (vt >= S) ? (vt - S) : vt;   // vt % S
            o4[idx4] = p4[row * 32 + (idx4 & 31)];
        }
    }
}

extern "C" void kernel_launch(void* const* d_in, const int* in_sizes, int n_in,
                              void* d_out, int out_size, void* d_ws, size_t ws_size,
                              hipStream_t stream) {
    const float* x       = (const float*)d_in[0];   // [2048,201,2] f32
    const int*   sol     = (const int*)d_in[1];     // [2048,201] int
    const float* W       = (const float*)d_in[2];   // [128,2] f32
    const float* pattern = (const float*)d_in[3];   // [201,128] f32
    float* out = (float*)d_out;

    hipLaunchKernelGGL(fused, dim3(B), dim3(TPB), 0, stream, x, sol, W, pattern, out);
}